// Round 3
// baseline (197.686 us; speedup 1.0000x reference)
//
#include <hip/hip_runtime.h>

#define DIM   1024
#define HEADS 16
#define NSEQ  2048
#define BATCH 2

typedef unsigned short u16;
typedef unsigned long long u64;
typedef __attribute__((ext_vector_type(8))) short bf16x8;    // 8 bf16 = 4 VGPRs
typedef __attribute__((ext_vector_type(4))) float f32x4;
typedef __attribute__((ext_vector_type(16))) float f32x16;

__device__ __forceinline__ u16 f2b(float f) {
  union { float f; unsigned u; } v; v.f = f;
  unsigned r = (v.u + 0x7fffu + ((v.u >> 16) & 1u)) >> 16;  // RNE
  return (u16)r;
}

// async global->LDS, 16B per lane; LDS dest is wave-uniform base + lane*16
__device__ __forceinline__ void g2l16(const u16* g, u16* l) {
  __builtin_amdgcn_global_load_lds(
      (const __attribute__((address_space(1))) void*)g,
      (__attribute__((address_space(3))) void*)l, 16, 0, 0);
}

// ---------------------------------------------------------------- fp32 -> bf16
// One fused kernel for all three tensors (was 3 launches).
// w_qkv's Q rows (first 1024*1024 elems) get scale*log2e folded in so the
// exp2 arg comes out of QK^T free.
#define N4_X  (4096 * 1024 / 4)
#define N4_W  (3072 * 1024 / 4)
#define N4_O  (1024 * 1024 / 4)
__global__ void cvt_all(const float* __restrict__ x, const float* __restrict__ wqkv,
                        const float* __restrict__ wout,
                        u16* __restrict__ xb, u16* __restrict__ wqkvb,
                        u16* __restrict__ woutb, float s) {
  int i = blockIdx.x * blockDim.x + threadIdx.x;   // grid sized exactly, no bound check
  const float* src; u16* dst; int j; float m = 1.0f;
  if (i < N4_X)            { src = x;    dst = xb;    j = i; }
  else if (i < N4_X + N4_W){ src = wqkv; dst = wqkvb; j = i - N4_X; if (j < 1024 * 1024 / 4) m = s; }
  else                     { src = wout; dst = woutb; j = i - N4_X - N4_W; }
  float4 f = ((const float4*)src)[j];
  union { u16 s[4]; u64 ll; } o;
  o.s[0] = f2b(f.x * m); o.s[1] = f2b(f.y * m);
  o.s[2] = f2b(f.z * m); o.s[3] = f2b(f.w * m);
  ((u64*)dst)[j] = o.ll;
}

// ------------------------------------------------- C = A[M,K] @ Bt[N,K]^T (+bias)
__global__ __launch_bounds__(256, 2)
void gemm_bt(const u16* __restrict__ A, const u16* __restrict__ Bt,
             void* __restrict__ C, const float* __restrict__ bias,
             int M, int Nc, int K, int bf16_out) {
  __shared__ u16 As[128 * 64];
  __shared__ u16 Bs[128 * 64];
  const int tid  = threadIdx.x;
  const int wave = tid >> 6, lane = tid & 63;
  const int l15  = lane & 15, quad = lane >> 4;
  const int m0 = blockIdx.y * 128, n0 = blockIdx.x * 128;
  const int wm = (wave >> 1) * 64, wn = (wave & 1) * 64;
  const int rb = wave * 32;

  f32x4 acc[4][4] = {};

  for (int kt = 0; kt < K; kt += 64) {
#pragma unroll
    for (int c = 0; c < 4; ++c) {
      int r  = rb + c * 8 + (lane >> 3);
      int ck = (lane & 7) ^ (r & 7);
      g2l16(A  + (size_t)(m0 + r) * K + kt + ck * 8, &As[(rb + c * 8) * 64]);
      g2l16(Bt + (size_t)(n0 + r) * K + kt + ck * 8, &Bs[(rb + c * 8) * 64]);
    }
    __syncthreads();
#pragma unroll
    for (int ks = 0; ks < 2; ++ks) {
      bf16x8 a[4], b[4];
      int ch = ks * 4 + quad;
#pragma unroll
      for (int i = 0; i < 4; ++i) {
        int ra  = wm + i * 16 + l15;
        a[i] = *(const bf16x8*)&As[ra * 64 + ((ch ^ (ra & 7)) << 3)];
        int rb2 = wn + i * 16 + l15;
        b[i] = *(const bf16x8*)&Bs[rb2 * 64 + ((ch ^ (rb2 & 7)) << 3)];
      }
#pragma unroll
      for (int i = 0; i < 4; ++i)
#pragma unroll
        for (int j = 0; j < 4; ++j)
          acc[i][j] = __builtin_amdgcn_mfma_f32_16x16x32_bf16(a[i], b[j], acc[i][j], 0, 0, 0);
    }
    __syncthreads();
  }

#pragma unroll
  for (int i = 0; i < 4; ++i)
#pragma unroll
    for (int j = 0; j < 4; ++j) {
      int row = m0 + wm + i * 16 + quad * 4;
      int col = n0 + wn + j * 16 + l15;
#pragma unroll
      for (int r = 0; r < 4; ++r) {
        float v = acc[i][j][r];
        if (bf16_out) ((u16*)C)[(size_t)(row + r) * Nc + col] = f2b(v);
        else          ((float*)C)[(size_t)(row + r) * Nc + col] = v + bias[col];
      }
    }
}

// --------------------------------------------------- flash attention v5
// 32x32x16 swapped-operand (S^T = K Q^T), lane owns q = lane&31.
// Fixed-max softmax (m=0); V rows permuted in LDS so P packs C-layout ->
// A-fragments with ZERO shfls (pa/pos formulas identical to v4b, j<64).
// v5: KV-SPLIT — 512-thread block, 8 waves; waves 0-3 = kv[0,1024),
//     waves 4-7 = kv[1024,2048), KVBLK=64 per group, same 128 q-rows.
//     LDS 64 KiB -> 2 blocks/CU -> 4 waves/SIMD (was 2). Fixed-max makes the
//     merge exact: O = O0+O1, l = l0+l1 via LDS epilogue.
// grid: (B*H, N/128), 512 threads, 2 blocks/CU.
__global__ __launch_bounds__(512, 4)
void attn(const u16* __restrict__ qkv, u16* __restrict__ outp) {
  __shared__ u16 Ks[2][2][64 * 64];    // [group][buf]; also Q staging / O-merge scratch
  __shared__ u16 Vts[2][2][64 * 64];   // [group][buf] permuted V^T rows d, 8 chunks of 8 j
  const int tid  = threadIdx.x;
  const int wave = tid >> 6, lane = tid & 63;
  const int g = wave >> 2, gw = wave & 3;       // KV group, wave-in-group
  const int l31  = lane & 31, h = lane >> 5;
  const int b = blockIdx.x >> 4, hd = blockIdx.x & 15;
  const int q0 = blockIdx.y * 128;
  const u16* base = qkv + (size_t)b * NSEQ * 3072;
  const int qoff = hd * 64, koff = DIM + hd * 64, voff = 2 * DIM + hd * 64;
  const int kv0 = g * 1024;
  // V staging: 256 threads/group, 2 j-rows per thread
  const int gt = tid & 255;
  const int dc = gt & 7, j0l = (gt >> 3) * 2;
  const int vchunk = (j0l >> 4) * 2 + ((j0l >> 2) & 1);
  const int vboff  = 4 * ((j0l >> 3) & 1) + (j0l & 3);   // in {0,2,4,6}

  union V4 { uint4 q; u16 s[8]; };
  union PA { unsigned w[4]; bf16x8 f; };

  u16* Kall = (u16*)Ks;   // 32 KiB; Q stage uses first 16 KiB (128 rows x 64)

  // ---- stage Q (128 rows, all 8 waves), pull B-fragments
#pragma unroll
  for (int c = 0; c < 2; ++c) {
    int bse = wave * 16 + c * 8;
    int r = bse + (lane >> 3);
    g2l16(base + (size_t)(q0 + r) * 3072 + qoff + (((lane & 7) ^ (r & 7)) << 3),
          &Kall[bse * 64]);
  }
  __syncthreads();
  bf16x8 qf[4];
  {
    int qr = gw * 32 + l31;
#pragma unroll
    for (int kd = 0; kd < 4; ++kd)
      qf[kd] = *(const bf16x8*)&Kall[qr * 64 + (((kd * 2 + h) ^ (qr & 7)) << 3)];
  }
  __syncthreads();

  // ---- stage tile 0 (per group)
  V4 vr[2];
#pragma unroll
  for (int c = 0; c < 2; ++c) {
    int bse = gw * 16 + c * 8;
    int r = bse + (lane >> 3);
    g2l16(base + (size_t)(kv0 + r) * 3072 + koff + (((lane & 7) ^ (r & 7)) << 3),
          &Ks[g][0][bse * 64]);
  }
#pragma unroll
  for (int e = 0; e < 2; ++e)
    vr[e].q = *(const uint4*)(base + (size_t)(kv0 + j0l + e) * 3072 + voff + dc * 8);
#pragma unroll
  for (int u = 0; u < 8; ++u) {
    int d = dc * 8 + u;
    unsigned w0 = (unsigned)vr[0].s[u] | ((unsigned)vr[1].s[u] << 16);
    *(unsigned*)&Vts[g][0][d * 64 + ((vchunk ^ ((d + (d >> 3)) & 7)) << 3) + vboff] = w0;
  }
  __syncthreads();

  float lrun = 0.0f;
  f32x16 oacc[2] = {};

  for (int t = 0; t < 16; ++t) {
    const int pbuf = t & 1;
    if (t < 15) {
      const int j0n = kv0 + (t + 1) * 64;
#pragma unroll
      for (int c = 0; c < 2; ++c) {
        int bse = gw * 16 + c * 8;
        int r = bse + (lane >> 3);
        g2l16(base + (size_t)(j0n + r) * 3072 + koff + (((lane & 7) ^ (r & 7)) << 3),
              &Ks[g][pbuf ^ 1][bse * 64]);
      }
#pragma unroll
      for (int e = 0; e < 2; ++e)
        vr[e].q = *(const uint4*)(base + (size_t)(j0n + j0l + e) * 3072 + voff + dc * 8);
    }

    // ---- S^T = K Q^T (exp2-ready logits: scale*log2e folded into Q)
    f32x16 sc[2] = {};
#pragma unroll
    for (int kd = 0; kd < 4; ++kd) {
      bf16x8 kb[2];
#pragma unroll
      for (int ni = 0; ni < 2; ++ni) {
        int kr = ni * 32 + l31;
        kb[ni] = *(const bf16x8*)&Ks[g][pbuf][kr * 64 + (((kd * 2 + h) ^ (kr & 7)) << 3)];
      }
#pragma unroll
      for (int ni = 0; ni < 2; ++ni)
        sc[ni] = __builtin_amdgcn_mfma_f32_32x32x16_bf16(kb[ni], qf[kd], sc[ni], 0, 0, 0);
    }

    // ---- exp2, l-accumulate, pack P directly into A-fragments (no shfl)
    PA pa[4];
#pragma unroll
    for (int ni = 0; ni < 2; ++ni) {
      f32x16 p;
#pragma unroll
      for (int r = 0; r < 16; ++r) p[r] = __builtin_amdgcn_exp2f(sc[ni][r]);
      float s0 = (p[0] + p[1]) + (p[2] + p[3]);
      float s1 = (p[4] + p[5]) + (p[6] + p[7]);
      float s2 = (p[8] + p[9]) + (p[10] + p[11]);
      float s3 = (p[12] + p[13]) + (p[14] + p[15]);
      lrun += (s0 + s1) + (s2 + s3);
#pragma unroll
      for (int ks2 = 0; ks2 < 2; ++ks2)
#pragma unroll
        for (int i = 0; i < 4; ++i) {
          unsigned lo = (__float_as_uint(p[8 * ks2 + 2 * i])     + 0x8000u) >> 16;
          unsigned hi = (__float_as_uint(p[8 * ks2 + 2 * i + 1]) + 0x8000u) & 0xFFFF0000u;
          pa[2 * ni + ks2].w[i] = lo | hi;
        }
    }

    // ---- O += P V  (V rows pre-permuted so pa's k-order matches)
#pragma unroll
    for (int f = 0; f < 4; ++f) {
      bf16x8 vb[2];
#pragma unroll
      for (int nd = 0; nd < 2; ++nd) {
        int d = nd * 32 + l31;
        vb[nd] = *(const bf16x8*)&Vts[g][pbuf][d * 64 + (((2 * f + h) ^ ((d + (d >> 3)) & 7)) << 3)];
      }
#pragma unroll
      for (int nd = 0; nd < 2; ++nd)
        oacc[nd] = __builtin_amdgcn_mfma_f32_32x32x16_bf16(pa[f].f, vb[nd], oacc[nd], 0, 0, 0);
    }

    // ---- commit prefetched V
    if (t < 15) {
#pragma unroll
      for (int u = 0; u < 8; ++u) {
        int d = dc * 8 + u;
        unsigned w0 = (unsigned)vr[0].s[u] | ((unsigned)vr[1].s[u] << 16);
        *(unsigned*)&Vts[g][pbuf ^ 1][d * 64 + ((vchunk ^ ((d + (d >> 3)) & 7)) << 3) + vboff] = w0;
      }
    }
    __syncthreads();
  }

  // ---- epilogue: merge the two KV-halves via LDS, normalize, store
  float* osh = (float*)Ks;    // 8192 f32 = 32 KiB: 4 waves x (2 x 16 x 64)
  float* lsh = (float*)Vts;
  if (g == 1) {
#pragma unroll
    for (int nd = 0; nd < 2; ++nd)
#pragma unroll
      for (int r = 0; r < 16; ++r)
        osh[gw * 2048 + (nd * 16 + r) * 64 + lane] = oacc[nd][r];
    lsh[gw * 64 + lane] = lrun;
  }
  __syncthreads();
  if (g == 0) {
    float lr = lrun + lsh[gw * 64 + lane];
    float l = lr + __shfl_xor(lr, 32, 64);
    float linv = 1.0f / l;
#pragma unroll
    for (int r = 0; r < 16; ++r) {
      int rowloc = (r & 3) + 8 * (r >> 2) + 4 * h;
      float lb = __shfl(linv, rowloc, 64);
      int row = q0 + gw * 32 + rowloc;
#pragma unroll
      for (int nd = 0; nd < 2; ++nd) {
        float o = oacc[nd][r] + osh[gw * 2048 + (nd * 16 + r) * 64 + lane];
        outp[((size_t)b * NSEQ + row) * DIM + hd * 64 + nd * 32 + l31] = f2b(o * lb);
      }
    }
  }
}

extern "C" void kernel_launch(void* const* d_in, const int* in_sizes, int n_in,
                              void* d_out, int out_size, void* d_ws, size_t ws_size,
                              hipStream_t stream) {
  const float* x     = (const float*)d_in[0];
  const float* w_qkv = (const float*)d_in[1];
  const float* w_out = (const float*)d_in[2];
  const float* b_out = (const float*)d_in[3];
  float* outp = (float*)d_out;

  u16* xb    = (u16*)d_ws;                        // 4096*1024
  u16* wqkvb = xb    + (size_t)4096 * 1024;       // 3072*1024
  u16* woutb = wqkvb + (size_t)3072 * 1024;       // 1024*1024
  u16* qkvb  = woutb + (size_t)1024 * 1024;       // 4096*3072
  u16* attnb = qkvb  + (size_t)4096 * 3072;       // 4096*1024

  const float C2 = 0.03125f * 1.44269504088896340736f;  // dim^-0.5 * log2(e)

  cvt_all<<<(N4_X + N4_W + N4_O) / 256, 256, 0, stream>>>(x, w_qkv, w_out,
                                                          xb, wqkvb, woutb, C2);

  gemm_bt<<<dim3(24, 32), 256, 0, stream>>>(xb, wqkvb, qkvb, nullptr, 4096, 3072, 1024, 1);
  attn<<<dim3(32, 16), 512, 0, stream>>>(qkvb, attnb);
  gemm_bt<<<dim3(8, 32), 256, 0, stream>>>(attnb, woutb, outp, b_out, 4096, 1024, 1024, 0);
}